// Round 10
// baseline (113.174 us; speedup 1.0000x reference)
//
#include <hip/hip_runtime.h>

#define NLAYERS 4
#define BATCH   64
#define LEN1    256
#define LEN2    256
#define DIM     1024
#define BKK     32
#define NKT     (DIM / BKK)   // 32 K-tiles

typedef _Float16 f16x8 __attribute__((ext_vector_type(8)));
typedef float    f32x4 __attribute__((ext_vector_type(4)));

typedef __attribute__((address_space(1))) const void gas_void;
typedef __attribute__((address_space(3))) void       las_void;

__device__ __forceinline__ void dma16(const float* g, float* l) {
  // 16-byte global->LDS DMA (no VGPR round trip)
  __builtin_amdgcn_global_load_lds((gas_void*)g, (las_void*)l, 16, 0, 0);
}

__device__ __forceinline__ void block_bar() {
  asm volatile("" ::: "memory");
  __builtin_amdgcn_s_barrier();
  asm volatile("" ::: "memory");
}

#define WAITVM(N) asm volatile("s_waitcnt vmcnt(" #N ")" ::: "memory")

// ---------------------------------------------------------------------------
// Kernel 1: one 1024-thread block per (nl, b); 16 waves, 4x4 wave grid, each
// wave owns a 64x64 output sub-tile.  A and B each read from global once.
//
// Structure (R9, verified): fp32 tiles staged straight into LDS via
// global_load_lds (no staging VGPRs, no cvt/ds_write chain); fp32->f16 at
// fragment-read time; raw s_barrier + counted vmcnt(4) keeps next-tile DMAs
// in flight across the whole compute phase.
//
// NEW (R10): per-block K-phase rotation ktp = (kt + bid) & 31.  Without it,
// all 256 lockstep blocks read the SAME 128 B column stripe of every 4 KB
// row at the same time -> demand concentrates on a 1/32 slice of address
// space mod 4KB (channel/L2-set hotspot).  Rotation decorrelates the column
// phase across blocks.  K-summation order per block changes (deterministic;
// fp32 rounding shift well within the 75x error margin); ssq is
// order-invariant.
//
// LDS layout per buffer/matrix: row-major [256][32] fp32, linear (DMA
// requirement); DMA's GLOBAL source column pre-swizzled ch ^ (row&7),
// readers apply the same involution.
// ---------------------------------------------------------------------------
__global__ __launch_bounds__(1024, 4)
void bs_main(const float* __restrict__ reps1, const float* __restrict__ reps2,
             const int* __restrict__ len1, const int* __restrict__ len2,
             float* __restrict__ feat) {
  __shared__ float Af[2][LEN1 * BKK];   // 2 x 32 KB
  __shared__ float Bf[2][LEN2 * BKK];   // 2 x 32 KB
  __shared__ float ssq1[LEN1];
  __shared__ float ssq2[LEN2];
  __shared__ float rowp[LEN1][4];       // per-row max partials (by wn)
  __shared__ float colp[LEN2][4];       // per-col max partials (by wm)
  __shared__ float redbuf[32];

  const int bid = blockIdx.x;
  const int nl  = bid >> 6;
  const int bb  = bid & 63;
  const float* gA = reps1 + (size_t)bid * LEN1 * DIM;
  const float* gB = reps2 + (size_t)bid * LEN2 * DIM;

  const int tid  = threadIdx.x;
  const int lane = tid & 63;
  const int wid  = tid >> 6;     // 16 waves
  const int wm   = wid >> 2;     // 0..3  (M, 64 rows each)
  const int wn   = wid & 3;      // 0..3  (N, 64 cols each)
  const int li   = lane & 15;
  const int lh   = lane >> 4;

  const int kph  = bid & (NKT - 1);   // per-block K-phase rotation

  f32x4 acc[4][4];
  #pragma unroll
  for (int a = 0; a < 4; ++a)
    #pragma unroll
    for (int c = 0; c < 4; ++c) acc[a][c] = 0.0f;

  // staging geometry: slot s (0..2047) = 16B chunk; row = s>>3, ch = s&7.
  // thread t owns slots t and t+1024 of both A and B.
  const int r0  = tid >> 3;            // row of slot j=0 (j=1: +128)
  const int ch0 = tid & 7;
  const int sc0 = (ch0 ^ (r0 & 7)) << 2;          // swizzled src col (floats)
  const int sc1 = (ch0 ^ ((r0 + 128) & 7)) << 2;

  float pssqA0 = 0.f, pssqA1 = 0.f, pssqB0 = 0.f, pssqB1 = 0.f;

  auto stage = [&](int kt, int buf) {
    const int col = ((kt + kph) & (NKT - 1)) * BKK;   // rotated K-tile
    dma16(gA + (size_t)r0 * DIM + col + sc0,          &Af[buf][tid * 4]);
    dma16(gB + (size_t)r0 * DIM + col + sc0,          &Bf[buf][tid * 4]);
    dma16(gA + (size_t)(r0 + 128) * DIM + col + sc1,  &Af[buf][(tid + 1024) * 4]);
    dma16(gB + (size_t)(r0 + 128) * DIM + col + sc1,  &Bf[buf][(tid + 1024) * 4]);
  };

  stage(0, 0);   // prologue: first (rotated) tile -> buffer 0

  #pragma unroll 1
  for (int kt = 0; kt < NKT; ++kt) {
    const int cur = kt & 1;
    if (kt + 1 < NKT) {
      stage(kt + 1, cur ^ 1);   // in flight across this whole tile's compute
      WAITVM(4);                // own tile-k DMAs done; k+1's stay in flight
    } else {
      WAITVM(0);
    }
    block_bar();                // BAR-B: everyone's tile-k data visible

    const float* Ac = Af[cur];
    const float* Bc = Bf[cur];

    // ---- ssq readback: each thread re-reads its own staged 64 B (linear)
    {
      const float4 a0 = *(const float4*)&Ac[tid * 4];
      const float4 a1 = *(const float4*)&Ac[(tid + 1024) * 4];
      const float4 b0 = *(const float4*)&Bc[tid * 4];
      const float4 b1 = *(const float4*)&Bc[(tid + 1024) * 4];
      pssqA0 += a0.x*a0.x + a0.y*a0.y + a0.z*a0.z + a0.w*a0.w;
      pssqA1 += a1.x*a1.x + a1.y*a1.y + a1.z*a1.z + a1.w*a1.w;
      pssqB0 += b0.x*b0.x + b0.y*b0.y + b0.z*b0.z + b0.w*b0.w;
      pssqB1 += b1.x*b1.x + b1.y*b1.y + b1.z*b1.z + b1.w*b1.w;
    }

    // ---- fragments: read fp32 (swizzled chunk), convert, MFMA
    f16x8 af[4];
    #pragma unroll
    for (int fm = 0; fm < 4; ++fm) {
      const int r = wm * 64 + fm * 16 + li;
      const float4 x0 = *(const float4*)&Ac[r * BKK + ((((lh << 1)    ) ^ (r & 7)) << 2)];
      const float4 x1 = *(const float4*)&Ac[r * BKK + ((((lh << 1) | 1) ^ (r & 7)) << 2)];
      f16x8 h;
      h[0] = (_Float16)x0.x; h[1] = (_Float16)x0.y; h[2] = (_Float16)x0.z; h[3] = (_Float16)x0.w;
      h[4] = (_Float16)x1.x; h[5] = (_Float16)x1.y; h[6] = (_Float16)x1.z; h[7] = (_Float16)x1.w;
      af[fm] = h;
    }
    #pragma unroll
    for (int fn = 0; fn < 4; ++fn) {
      const int r = wn * 64 + fn * 16 + li;
      const float4 y0 = *(const float4*)&Bc[r * BKK + ((((lh << 1)    ) ^ (r & 7)) << 2)];
      const float4 y1 = *(const float4*)&Bc[r * BKK + ((((lh << 1) | 1) ^ (r & 7)) << 2)];
      f16x8 bh;
      bh[0] = (_Float16)y0.x; bh[1] = (_Float16)y0.y; bh[2] = (_Float16)y0.z; bh[3] = (_Float16)y0.w;
      bh[4] = (_Float16)y1.x; bh[5] = (_Float16)y1.y; bh[6] = (_Float16)y1.z; bh[7] = (_Float16)y1.w;
      #pragma unroll
      for (int fm = 0; fm < 4; ++fm)
        acc[fm][fn] = __builtin_amdgcn_mfma_f32_16x16x32_f16(af[fm], bh, acc[fm][fn], 0, 0, 0);
    }

    block_bar();                // BAR-A: reads of cur done before next DMA
  }

  // ---- norms: reduce the 8 chunk-threads of each row (lane bits 0..2)
  #pragma unroll
  for (int m = 1; m <= 4; m <<= 1) {
    pssqA0 += __shfl_xor(pssqA0, m, 64);
    pssqA1 += __shfl_xor(pssqA1, m, 64);
    pssqB0 += __shfl_xor(pssqB0, m, 64);
    pssqB1 += __shfl_xor(pssqB1, m, 64);
  }
  if ((lane & 7) == 0) {
    ssq1[r0] = pssqA0;  ssq1[r0 + 128] = pssqA1;
    ssq2[r0] = pssqB0;  ssq2[r0 + 128] = pssqB1;
  }
  __syncthreads();
  if (tid < 256)       ssq1[tid] = 1.0f / sqrtf(ssq1[tid]);
  else if (tid < 512)  ssq2[tid - 256] = 1.0f / sqrtf(ssq2[tid - 256]);
  __syncthreads();

  const int n1 = len1[bb];
  const int n2 = len2[bb];

  float rn2v[4];
  bool  jv[4];
  #pragma unroll
  for (int fn = 0; fn < 4; ++fn) {
    const int j = wn * 64 + fn * 16 + li;
    rn2v[fn] = ssq2[j];
    jv[fn]   = (j < n2);
  }
  float rn1v[4][4];
  bool  iv[4][4];
  #pragma unroll
  for (int fm = 0; fm < 4; ++fm)
    #pragma unroll
    for (int rg = 0; rg < 4; ++rg) {
      const int i = wm * 64 + fm * 16 + lh * 4 + rg;
      rn1v[fm][rg] = ssq1[i];
      iv[fm][rg]   = (i < n1);
    }

  const float NEG = -3.402823466e38f;
  float rowm[4][4];
  float colm[4];
  #pragma unroll
  for (int fm = 0; fm < 4; ++fm)
    #pragma unroll
    for (int rg = 0; rg < 4; ++rg) rowm[fm][rg] = NEG;
  #pragma unroll
  for (int fn = 0; fn < 4; ++fn) colm[fn] = NEG;

  #pragma unroll
  for (int fm = 0; fm < 4; ++fm)
    #pragma unroll
    for (int fn = 0; fn < 4; ++fn)
      #pragma unroll
      for (int rg = 0; rg < 4; ++rg) {
        const float v = acc[fm][fn][rg] * rn1v[fm][rg] * rn2v[fn];
        if (jv[fn] && v > rowm[fm][rg]) rowm[fm][rg] = v;
        if (iv[fm][rg] && v > colm[fn]) colm[fn] = v;
      }

  // row maxima: reduce across li (lane bits 0..3)
  #pragma unroll
  for (int m = 1; m <= 8; m <<= 1)
    #pragma unroll
    for (int fm = 0; fm < 4; ++fm)
      #pragma unroll
      for (int rg = 0; rg < 4; ++rg) {
        const float o = __shfl_xor(rowm[fm][rg], m, 64);
        rowm[fm][rg] = fmaxf(rowm[fm][rg], o);
      }
  // col maxima: reduce across lh (lane bits 4..5)
  #pragma unroll
  for (int m = 16; m <= 32; m <<= 1)
    #pragma unroll
    for (int fn = 0; fn < 4; ++fn) {
      const float o = __shfl_xor(colm[fn], m, 64);
      colm[fn] = fmaxf(colm[fn], o);
    }

  if (li == 0)
    #pragma unroll
    for (int fm = 0; fm < 4; ++fm)
      #pragma unroll
      for (int rg = 0; rg < 4; ++rg)
        rowp[wm * 64 + fm * 16 + lh * 4 + rg][wn] = rowm[fm][rg];
  if (lh == 0)
    #pragma unroll
    for (int fn = 0; fn < 4; ++fn)
      colp[wn * 64 + fn * 16 + li][wm] = colm[fn];
  __syncthreads();

  float c1 = 0.f, c2 = 0.f;
  if (tid < 256) {
    const float rm = fmaxf(fmaxf(rowp[tid][0], rowp[tid][1]),
                           fmaxf(rowp[tid][2], rowp[tid][3]));
    if (tid < n1) c2 = rm;
    const float cm = fmaxf(fmaxf(colp[tid][0], colp[tid][1]),
                           fmaxf(colp[tid][2], colp[tid][3]));
    if (tid < n2) c1 = cm;
  }
  #pragma unroll
  for (int m = 1; m <= 32; m <<= 1) {
    c1 += __shfl_xor(c1, m, 64);
    c2 += __shfl_xor(c2, m, 64);
  }
  if (lane == 0) {
    redbuf[wid]      = c1;
    redbuf[16 + wid] = c2;
  }
  __syncthreads();
  if (tid == 0) {
    float s1s = 0.f, s2s = 0.f;
    #pragma unroll
    for (int i = 0; i < 16; ++i) { s1s += redbuf[i]; s2s += redbuf[16 + i]; }
    const float s1 = s1s / (float)n2;
    const float s2 = s2s / (float)n1;
    feat[bb * NLAYERS + nl] = 2.0f * s1 * s2 / (s1 + s2);
  }
}

// ---------------------------------------------------------------------------
// Kernel 2: BatchNorm1d (batch stats, biased var) + linear head -> out[b]
// ---------------------------------------------------------------------------
__global__ void bs_head(const float* __restrict__ feat, const float* __restrict__ w,
                        const float* __restrict__ bias, float* __restrict__ out) {
  __shared__ float lds[NLAYERS][BATCH];
  const int tid = threadIdx.x;
  const int nl  = tid >> 6;
  const int b   = tid & 63;

  const float x = feat[b * NLAYERS + nl];
  float s = x;
  #pragma unroll
  for (int m = 1; m <= 32; m <<= 1) s += __shfl_xor(s, m, 64);
  const float mean = s / 64.0f;
  const float d = x - mean;
  float v = d * d;
  #pragma unroll
  for (int m = 1; m <= 32; m <<= 1) v += __shfl_xor(v, m, 64);
  const float var = v / 64.0f;
  const float y = d / sqrtf(var + 1e-8f);

  lds[nl][b] = y * w[nl];
  __syncthreads();
  if (tid < 64)
    out[tid] = lds[0][tid] + lds[1][tid] + lds[2][tid] + lds[3][tid] + bias[0];
}

extern "C" void kernel_launch(void* const* d_in, const int* in_sizes, int n_in,
                              void* d_out, int out_size, void* d_ws, size_t ws_size,
                              hipStream_t stream) {
  const float* reps1 = (const float*)d_in[0];
  const float* reps2 = (const float*)d_in[1];
  const int*   len1  = (const int*)d_in[2];
  const int*   len2  = (const int*)d_in[3];
  const float* w     = (const float*)d_in[4];
  const float* bias  = (const float*)d_in[5];
  float* feat = (float*)d_ws;   // 256 floats

  bs_main<<<NLAYERS * BATCH, 1024, 0, stream>>>(reps1, reps2, len1, len2, feat);
  bs_head<<<1, 256, 0, stream>>>(feat, w, bias, (float*)d_out);
}